// Round 4
// baseline (4838.747 us; speedup 1.0000x reference)
//
#include <hip/hip_runtime.h>

// VanillaRNN B=64,S=2048,I=128,H=512,O=128. ALL inputs fp32; OUTPUT fp32
// (outputs [64][2048][128] then h_final [64][512], flat-concatenated fp32).
//
// Single fused kernel: 128 blocks x 512 threads; block pair (2b,2b+1) owns
// batch b. Each WG holds its 256x512 W_rec slice + W_in slice + 64x512 W_out
// slice in VGPRs as fp16 (v_dot2_f32_f16 path, fp32 accumulate). Per step:
//   - GEMV h-pre-activations from LDS h (half2, bank-conflict-free chunked
//     layout), fused input projection from LDS x (prefetched one step ahead),
//     PLUS output row t-1 = W_out . h_t reusing the same LDS h loads.
//   - 8-lane butterfly reduce, tanh on c==0 lanes, write own h slice to LDS,
//     publish 256 h values to partner WG via tagged u64 agent-scope atomic
//     stores (tag = t+1, double-buffered by step parity), pull partner's.
// Epilogue computes output row S-1 from h_S. h_final written at t=S-1.
// ws usage: exchange slots only, [B][2 wg][2 parity][128] u64 = 256 KiB.
// Poison 0xAA.. never matches tags 1..2048, so re-poisoned ws is safe.
// 128 WGs <= 256 CUs -> all co-resident, exchange cannot deadlock.

typedef _Float16 half2_t __attribute__((ext_vector_type(2)));
typedef _Float16 half8_t __attribute__((ext_vector_type(8)));
typedef float    float2_t __attribute__((ext_vector_type(2)));
typedef float    float4_t __attribute__((ext_vector_type(4)));

#define BB 64
#define SS 2048
#define IN 128
#define HH 512
#define OO 128

using u32 = unsigned int;
using u64 = unsigned long long;

__device__ __forceinline__ float fdot2f(half2_t a, half2_t b, float c) {
#if __has_builtin(__builtin_amdgcn_fdot2)
    return __builtin_amdgcn_fdot2(a, b, c, false);
#else
    return c + (float)a[0] * (float)b[0] + (float)a[1] * (float)b[1];
#endif
}
__device__ __forceinline__ half2_t h2(float a, float b) {
    return half2_t{(_Float16)a, (_Float16)b};
}

__global__ __launch_bounds__(512, 2) void rnn_fused(
    const float* __restrict__ inputs,   // [B][S][I]
    const float* __restrict__ h0,       // [B][H]
    const float* __restrict__ W_in,     // [H][I]
    const float* __restrict__ W_in_b,   // [H]
    const float* __restrict__ W_rec,    // [H][H]
    const float* __restrict__ W_out,    // [O][H]
    const float* __restrict__ W_out_b,  // [O]
    float* __restrict__ outp,           // fp32 [B][S][O]
    float* __restrict__ hfinal,         // fp32 [B][H]
    u64* __restrict__ hex)              // [B][2][2][128]
{
    const int tid = threadIdx.x;
    const int bb = blockIdx.x >> 1;
    const int w  = blockIdx.x & 1;     // which half of H this WG produces
    const int c  = tid & 7;            // k-chunk (64 h values each)
    const int q  = tid >> 3;           // j-quad / o index
    const int og = w * 64 + q;         // this thread-group's output column

    // h as half2, chunk-strided 36 dwords: lane c's b128 reads start at
    // bank (9c+kb*4)%32 -> distinct across the 8 c-lanes, conflict-free.
    __shared__ __align__(16) half2_t hbuf[288];
    // input row as half2, chunk stride 12 dwords, double-buffered.
    __shared__ __align__(16) half2_t xh[2][96];

    // ---- persistent weights in VGPRs (fp32 -> fp16 once)
    half2_t wr[4][32];   // W_rec[jg][c*64 + 2m..]
    half2_t wi[4][8];    // W_in [jg][c*16 + 2m..]
    half2_t wo[32];      // W_out[og][c*64 + 2m..]
    float bias[4];

    #pragma unroll
    for (int jj = 0; jj < 4; ++jj) {
        const int jg = w * 256 + q * 4 + jj;
        const float4_t* rrow = (const float4_t*)(W_rec + jg * HH + c * 64);
        #pragma unroll
        for (int m = 0; m < 16; ++m) {
            const float4_t u = rrow[m];
            wr[jj][m * 2 + 0] = h2(u[0], u[1]);
            wr[jj][m * 2 + 1] = h2(u[2], u[3]);
        }
        const float4_t* irow = (const float4_t*)(W_in + jg * IN + c * 16);
        #pragma unroll
        for (int m = 0; m < 4; ++m) {
            const float4_t u = irow[m];
            wi[jj][m * 2 + 0] = h2(u[0], u[1]);
            wi[jj][m * 2 + 1] = h2(u[2], u[3]);
        }
        bias[jj] = W_in_b[jg];
    }
    {
        const float4_t* orow = (const float4_t*)(W_out + og * HH + c * 64);
        #pragma unroll
        for (int m = 0; m < 16; ++m) {
            const float4_t u = orow[m];
            wo[m * 2 + 0] = h2(u[0], u[1]);
            wo[m * 2 + 1] = h2(u[2], u[3]);
        }
    }
    const float bo = W_out_b[og];

    // ---- init LDS: h = h0 (fp32->fp16), x row 0
    if (tid < 256) {
        const float2_t u = *(const float2_t*)(h0 + bb * HH + tid * 2);
        const int k = tid * 2;
        hbuf[(k >> 6) * 36 + ((k & 63) >> 1)] = h2(u[0], u[1]);
    }
    if (tid >= 256 && tid < 320) {
        const int i2 = tid - 256;
        const float2_t u = *(const float2_t*)(inputs +
                              (size_t)(bb * SS + 0) * IN + i2 * 2);
        xh[0][(i2 >> 3) * 12 + (i2 & 7)] = h2(u[0], u[1]);
    }
    __syncthreads();

    for (int t = 0; t < SS; ++t) {
        // ---- recurrence partials + output-row(t-1) partials, lane's k-chunk
        float acc[4] = {0.f, 0.f, 0.f, 0.f};
        float oa = 0.f;
        const half2_t* hb = &hbuf[c * 36];
        #pragma unroll
        for (int kb = 0; kb < 8; ++kb) {
            const half8_t hv = *(const half8_t*)(hb + kb * 4);
            const half2_t p0 = __builtin_shufflevector(hv, hv, 0, 1);
            const half2_t p1 = __builtin_shufflevector(hv, hv, 2, 3);
            const half2_t p2 = __builtin_shufflevector(hv, hv, 4, 5);
            const half2_t p3 = __builtin_shufflevector(hv, hv, 6, 7);
            #pragma unroll
            for (int jj = 0; jj < 4; ++jj) {
                acc[jj] = fdot2f(wr[jj][kb * 4 + 0], p0, acc[jj]);
                acc[jj] = fdot2f(wr[jj][kb * 4 + 1], p1, acc[jj]);
                acc[jj] = fdot2f(wr[jj][kb * 4 + 2], p2, acc[jj]);
                acc[jj] = fdot2f(wr[jj][kb * 4 + 3], p3, acc[jj]);
            }
            oa = fdot2f(wo[kb * 4 + 0], p0, oa);
            oa = fdot2f(wo[kb * 4 + 1], p1, oa);
            oa = fdot2f(wo[kb * 4 + 2], p2, oa);
            oa = fdot2f(wo[kb * 4 + 3], p3, oa);
        }
        // ---- fused input projection (lane's 16 of 128 inputs)
        {
            const half2_t* xb = &xh[t & 1][c * 12];
            const half8_t xv0 = *(const half8_t*)(xb);
            const half8_t xv1 = *(const half8_t*)(xb + 4);
            const half2_t x0 = __builtin_shufflevector(xv0, xv0, 0, 1);
            const half2_t x1 = __builtin_shufflevector(xv0, xv0, 2, 3);
            const half2_t x2 = __builtin_shufflevector(xv0, xv0, 4, 5);
            const half2_t x3 = __builtin_shufflevector(xv0, xv0, 6, 7);
            const half2_t x4 = __builtin_shufflevector(xv1, xv1, 0, 1);
            const half2_t x5 = __builtin_shufflevector(xv1, xv1, 2, 3);
            const half2_t x6 = __builtin_shufflevector(xv1, xv1, 4, 5);
            const half2_t x7 = __builtin_shufflevector(xv1, xv1, 6, 7);
            #pragma unroll
            for (int jj = 0; jj < 4; ++jj) {
                acc[jj] = fdot2f(wi[jj][0], x0, acc[jj]);
                acc[jj] = fdot2f(wi[jj][1], x1, acc[jj]);
                acc[jj] = fdot2f(wi[jj][2], x2, acc[jj]);
                acc[jj] = fdot2f(wi[jj][3], x3, acc[jj]);
                acc[jj] = fdot2f(wi[jj][4], x4, acc[jj]);
                acc[jj] = fdot2f(wi[jj][5], x5, acc[jj]);
                acc[jj] = fdot2f(wi[jj][6], x6, acc[jj]);
                acc[jj] = fdot2f(wi[jj][7], x7, acc[jj]);
            }
        }
        // ---- butterfly reduce over the 8 c-lanes
        #pragma unroll
        for (int jj = 0; jj < 4; ++jj) {
            float v = acc[jj];
            v += __shfl_xor(v, 1);
            v += __shfl_xor(v, 2);
            v += __shfl_xor(v, 4);
            acc[jj] = v;
        }
        oa += __shfl_xor(oa, 1);
        oa += __shfl_xor(oa, 2);
        oa += __shfl_xor(oa, 4);

        __syncthreads();   // all hbuf/xh reads of step t complete

        if (c == 0) {
            if (t > 0)
                outp[(size_t)(bb * SS + (t - 1)) * OO + og] = oa + bo;
            const float v0 = tanhf(acc[0] + bias[0]);
            const float v1 = tanhf(acc[1] + bias[1]);
            const float v2 = tanhf(acc[2] + bias[2]);
            const float v3 = tanhf(acc[3] + bias[3]);
            const half2_t ha = h2(v0, v1);
            const half2_t hc = h2(v2, v3);
            const u32 la = __builtin_bit_cast(u32, ha);
            const u32 lb = __builtin_bit_cast(u32, hc);
            const int kg = w * 256 + q * 4;
            const int pos = (kg >> 6) * 36 + ((kg & 63) >> 1);
            hbuf[pos]     = ha;
            hbuf[pos + 1] = hc;
            const u64 taghi = ((u64)(u32)(t + 1)) << 32;
            const int sbase = ((bb * 2 + w) * 2 + (t & 1)) * 128 + q * 2;
            __hip_atomic_store(&hex[sbase],     taghi | la,
                               __ATOMIC_RELAXED, __HIP_MEMORY_SCOPE_AGENT);
            __hip_atomic_store(&hex[sbase + 1], taghi | lb,
                               __ATOMIC_RELAXED, __HIP_MEMORY_SCOPE_AGENT);
            if (t == SS - 1) {
                *(float4_t*)(&hfinal[bb * HH + w * 256 + q * 4]) =
                    float4_t{v0, v1, v2, v3};
            }
        }
        // ---- pull partner's 256 h values (tagged, parity-double-buffered)
        if (tid < 128) {
            const int pw = 1 - w;
            const int sidx = ((bb * 2 + pw) * 2 + (t & 1)) * 128 + tid;
            u64 v;
            do {
                v = __hip_atomic_load(&hex[sidx], __ATOMIC_RELAXED,
                                      __HIP_MEMORY_SCOPE_AGENT);
            } while ((u32)(v >> 32) != (u32)(t + 1));
            const int kg = pw * 256 + tid * 2;
            hbuf[(kg >> 6) * 36 + ((kg & 63) >> 1)] =
                __builtin_bit_cast(half2_t, (u32)v);
        }
        // ---- prefetch next input row
        if (tid >= 256 && tid < 320) {
            const int tn = t + 1;
            if (tn < SS) {
                const int i2 = tid - 256;
                const float2_t u = *(const float2_t*)(inputs +
                                      (size_t)(bb * SS + tn) * IN + i2 * 2);
                xh[tn & 1][(i2 >> 3) * 12 + (i2 & 7)] = h2(u[0], u[1]);
            }
        }
        __syncthreads();   // hbuf fully updated for step t+1
    }

    // ---- epilogue: output row S-1 = W_out . h_S (+ bias)
    {
        float oa = 0.f;
        const half2_t* hb = &hbuf[c * 36];
        #pragma unroll
        for (int kb = 0; kb < 8; ++kb) {
            const half8_t hv = *(const half8_t*)(hb + kb * 4);
            oa = fdot2f(wo[kb * 4 + 0], __builtin_shufflevector(hv, hv, 0, 1), oa);
            oa = fdot2f(wo[kb * 4 + 1], __builtin_shufflevector(hv, hv, 2, 3), oa);
            oa = fdot2f(wo[kb * 4 + 2], __builtin_shufflevector(hv, hv, 4, 5), oa);
            oa = fdot2f(wo[kb * 4 + 3], __builtin_shufflevector(hv, hv, 6, 7), oa);
        }
        oa += __shfl_xor(oa, 1);
        oa += __shfl_xor(oa, 2);
        oa += __shfl_xor(oa, 4);
        if (c == 0)
            outp[(size_t)(bb * SS + (SS - 1)) * OO + og] = oa + bo;
    }
}

// ---------------------------------------------------------------- launcher
extern "C" void kernel_launch(void* const* d_in, const int* in_sizes, int n_in,
                              void* d_out, int out_size, void* d_ws, size_t ws_size,
                              hipStream_t stream) {
    const float* inputs  = (const float*)d_in[0];
    const float* h0      = (const float*)d_in[1];
    const float* W_in_w  = (const float*)d_in[2];
    const float* W_in_b  = (const float*)d_in[3];
    const float* W_rec_w = (const float*)d_in[4];
    const float* W_out_w = (const float*)d_in[5];
    const float* W_out_b = (const float*)d_in[6];

    float* out    = (float*)d_out;                   // fp32 outputs
    float* hfinal = out + (size_t)BB * SS * OO;      // fp32 h_final
    u64* hex      = (u64*)d_ws;                      // 256 KiB exchange

    rnn_fused<<<dim3(BB * 2), dim3(512), 0, stream>>>(
        inputs, h0, W_in_w, W_in_b, W_rec_w, W_out_w, W_out_b,
        out, hfinal, hex);
}